// Round 2
// baseline (180.922 us; speedup 1.0000x reference)
//
#include <hip/hip_runtime.h>

// BoundarySeg: B=16, L=1024, H=768, MAX_SPAN_LEN=6 — all fp32
//   w[b,j,d]     = span[b, j, min(j+d,L-1), 0] * (j+d < L)
//   first[b,j,h] = sum_d w[b,j,d] * bound[b, min(j+d,L-1), h]
//   second[b,j,h]= bound[b,j,h] * sum_d w[b,j,d]
//   out = concat(first, second, axis=-1) -> (B, L, 1536)
//
// R6: register-window streaming, NO LDS, NO barriers.
//   R5 post-mortem: dur 182->179.5 with fills 59->65 us => kernel ~64->~50 us.
//   Still 1.8x off the 28 us traffic roofline. The LDS double-buffer caps
//   occupancy at 80.4 KB -> 2 blocks/CU = 6 waves/CU (1.5/SIMD) — too few
//   in-flight requests for a 900-cycle HBM stream; and the 6-row reuse window
//   fits in registers anyway, so LDS+barriers were pure overhead.
//   Design:
//    * block = 384 thr (6 waves); thread owns one f32x2 column (384 x 2 = 768)
//    * block walks a 16-row chunk + 5-row halo: read amp 21/16 = 1.31
//      (reads 66 MB + writes 101 MB ~= 171 MB -> ~25 us @ 6.8 TB/s)
//    * grid = 16 batches x 64 chunks = 1024 blocks -> 24 waves/CU (4x R5)
//    * full unroll: 21 row-loads hoisted (21 outstanding reqs/wave), then
//      16 compute+store steps drain with per-use vmcnt waits
//    * span weights are block-uniform -> SALU loads, free broadcast
//   Predict kernel ~50 -> ~28-33 us; dur_us 179.5 -> ~155-162.

#define LROWS 1024
#define HDIM  768
#define SPANW 6
#define HALO  (SPANW - 1)
#define RCHUNK 16                    // rows per block
#define CHUNKS (LROWS / RCHUNK)      // 64
#define BLK   384                    // threads = 6 waves; f32x2 columns

typedef float f32x2 __attribute__((ext_vector_type(2)));

__global__ __launch_bounds__(BLK) void boundary_seg_kernel(
    const float* __restrict__ span,   // (B, L, L, 1)
    const float* __restrict__ bound,  // (B, L, H)
    float* __restrict__ out)          // (B, L, 2H)
{
    const int tid  = threadIdx.x;
    const int b    = blockIdx.x >> 6;                 // / CHUNKS
    const int j0   = (blockIdx.x & (CHUNKS - 1)) * RCHUNK;
    const int bL   = b * LROWS;
    const int colf = tid << 1;                        // float col 0..766

    // ---- load the 21-row window for this column into registers
    const float* bcol = bound + (size_t)bL * HDIM + colf;
    f32x2 h[RCHUNK + HALO];
#pragma unroll
    for (int r = 0; r < RCHUNK + HALO; ++r) {
        int gr = j0 + r;                              // uniform per step
        if (gr > LROWS - 1) gr = LROWS - 1;           // only last chunk clamps
        h[r] = *(const f32x2*)(bcol + (size_t)gr * HDIM);
    }

    // span row j, starting col j:  diagonal walk, +1025 floats per step
    const float* sdiag = span + (size_t)(bL + j0) * LROWS + j0;

#pragma unroll
    for (int s = 0; s < RCHUNK; ++s) {
        const int j = j0 + s;
        const float* sp = sdiag + (size_t)s * (LROWS + 1);

        float w[SPANW], wsum = 0.f;                   // block-uniform -> SGPRs
#pragma unroll
        for (int d = 0; d < SPANW; ++d) {
            w[d] = (j + d < LROWS) ? sp[d] : 0.f;
            wsum += w[d];
        }

        f32x2 acc = w[0] * h[s]     + w[1] * h[s + 1] + w[2] * h[s + 2]
                  + w[3] * h[s + 3] + w[4] * h[s + 4] + w[5] * h[s + 5];
        const f32x2 sec = h[s] * wsum;

        float* orow = out + (size_t)(bL + j) * (2 * HDIM) + colf;
        *(f32x2*)orow          = acc;
        *(f32x2*)(orow + HDIM) = sec;
    }
}

extern "C" void kernel_launch(void* const* d_in, const int* in_sizes, int n_in,
                              void* d_out, int out_size, void* d_ws, size_t ws_size,
                              hipStream_t stream) {
    const float* span  = (const float*)d_in[0];
    const float* bound = (const float*)d_in[1];
    float* out = (float*)d_out;

    const int B = in_sizes[1] / (LROWS * HDIM);       // 16 (element count)
    dim3 grid(B * CHUNKS), block(BLK);                // 1024 x 384
    hipLaunchKernelGGL(boundary_seg_kernel, grid, block, 0, stream,
                       span, bound, out);
}

// Round 4
// 175.447 us; speedup vs baseline: 1.0312x; 1.0312x over previous
//
#include <hip/hip_runtime.h>

// BoundarySeg: B=16, L=1024, H=768, MAX_SPAN_LEN=6 — all fp32
//   w[b,j,d]     = span[b, j, min(j+d,L-1), 0] * (j+d < L)
//   first[b,j,h] = sum_d w[b,j,d] * bound[b, min(j+d,L-1), h]
//   second[b,j,h]= bound[b,j,h] * sum_d w[b,j,d]
//   out = concat(first, second, axis=-1) -> (B, L, 1536)
//
// R8 = R7 resubmitted verbatim (R7 bench was an infra failure: "MI355X
// container failed twice" — kernel never ran; no compile/correctness signal).
//
// R7 theory: fix R6's two wounds, keep register-window streaming.
//   Ledger: flat=2x59+65, R0=2x59+64, R5=2x65+49.5, R6=2x65+51 -> kernel ~51 us,
//   still 2x off the 25-28 us floor (~160 MB HBM; bound is L3-resident).
//   R6 flaws: (1) every thread issued the same 96 uniform span loads inside the
//   unrolled loop -> register-pressure bomb (h[21]+96 temps -> probable scratch
//   spill) or 16 exposed VMEM latency chains; (2) 8 B/lane (f32x2) accesses.
//   R7:
//    * span weights staged ONCE into 512 B LDS (16 rows x [6 w + wsum + pad]),
//      one barrier, then conflict-free broadcast ds_read_b128 per step
//    * f32x4 columns: BLK=192 (3 waves), thread owns 1 of 192 columns;
//      h[21]x4 = 84 VGPR + misc -> 16-wave class, __launch_bounds__(192,4)
//    * grid 1024 = 16 b x 64 chunks of 16 rows; amp 21/16 = 1.31 (L3-absorbed)
//    * chunked XCD swizzle: 128 consecutive chunks per XCD -> halo L2 reuse
//   Predict kernel ~51 -> ~30: dur 180.9 -> ~158-166. If >=176: next round
//   double-launch diagnostic to read kernel time straight out of dur delta.

#define LROWS 1024
#define HDIM  768
#define SPANW 6
#define HALO  (SPANW - 1)
#define RCHUNK 16
#define CHUNKS (LROWS / RCHUNK)      // 64
#define BLK   192                    // 3 waves; one f32x4 column per thread

typedef float f32x4 __attribute__((ext_vector_type(4)));

__global__ __launch_bounds__(BLK, 4) void boundary_seg_kernel(
    const float* __restrict__ span,   // (B, L, L, 1)
    const float* __restrict__ bound,  // (B, L, H)
    float* __restrict__ out)          // (B, L, 2H)
{
    __shared__ float sw[RCHUNK][8];   // [r] = {w0..w5, wsum, pad} — 512 B

    const int tid = threadIdx.x;

    // chunked XCD swizzle (gridDim.x = 1024, %8 == 0 -> bijective):
    // XCD x gets original block ids [x*128, (x+1)*128) -> neighbor chunks
    // (sharing 5-row halos) land on the same XCD's L2.
    const unsigned nwg = gridDim.x;
    const unsigned wg  = (nwg & 7u) ? blockIdx.x
                       : (blockIdx.x & 7u) * (nwg >> 3) + (blockIdx.x >> 3);

    const int b    = wg >> 6;                    // / CHUNKS
    const int j0   = (wg & (CHUNKS - 1)) * RCHUNK;
    const int bL   = b * LROWS;
    const int colf = tid << 2;                   // float col, 16 B/lane

    // ---- preload the 21-row window for this column (21 independent loads)
    const float* bcol = bound + (size_t)bL * HDIM + colf;
    f32x4 h[RCHUNK + HALO];
#pragma unroll
    for (int r = 0; r < RCHUNK + HALO; ++r) {
        int gr = j0 + r;
        if (gr > LROWS - 1) gr = LROWS - 1;      // only last chunk clamps
        h[r] = *(const f32x4*)(bcol + (size_t)gr * HDIM);
    }

    // ---- stage span weights: one thread per row (wave 0 only)
    if (tid < RCHUNK) {
        const int j = j0 + tid;
        const float* sp = span + (size_t)(bL + j) * LROWS + j;
        float wsum = 0.f;
#pragma unroll
        for (int d = 0; d < SPANW; ++d) {
            const float v = (j + d < LROWS) ? sp[d] : 0.f;
            sw[tid][d] = v;
            wsum += v;
        }
        sw[tid][6] = wsum;
        sw[tid][7] = 0.f;
    }
    __syncthreads();

    // ---- 16 compute+store steps; w via conflict-free LDS broadcast
#pragma unroll
    for (int s = 0; s < RCHUNK; ++s) {
        const f32x4 w0 = *(const f32x4*)&sw[s][0];   // w0..w3
        const f32x4 w1 = *(const f32x4*)&sw[s][4];   // w4, w5, wsum, pad

        f32x4 acc = w0[0] * h[s]     + w0[1] * h[s + 1] + w0[2] * h[s + 2]
                  + w0[3] * h[s + 3] + w1[0] * h[s + 4] + w1[1] * h[s + 5];
        const f32x4 sec = h[s] * w1[2];

        float* orow = out + (size_t)(bL + j0 + s) * (2 * HDIM) + colf;
        *(f32x4*)orow          = acc;
        *(f32x4*)(orow + HDIM) = sec;
    }
}

extern "C" void kernel_launch(void* const* d_in, const int* in_sizes, int n_in,
                              void* d_out, int out_size, void* d_ws, size_t ws_size,
                              hipStream_t stream) {
    const float* span  = (const float*)d_in[0];
    const float* bound = (const float*)d_in[1];
    float* out = (float*)d_out;

    const int B = in_sizes[1] / (LROWS * HDIM);       // 16 (element count)
    dim3 grid(B * CHUNKS), block(BLK);                // 1024 x 192
    hipLaunchKernelGGL(boundary_seg_kernel, grid, block, 0, stream,
                       span, bound, out);
}